// Round 10
// baseline (256.810 us; speedup 1.0000x reference)
//
#include <hip/hip_runtime.h>
#include <hip/hip_bf16.h>

#define NEG_INF -9.0e15f

using u16 = unsigned short;

__device__ __forceinline__ float b2f(__hip_bfloat16 v) { return __bfloat162float(v); }
__device__ __forceinline__ float ldv(const float* p, int i) { return p[i]; }
__device__ __forceinline__ float ldv(const __hip_bfloat16* p, int i) { return __bfloat162float(p[i]); }
__device__ __forceinline__ float bu2f(u16 u) { return __uint_as_float(((unsigned)u) << 16); }

__device__ __forceinline__ void async16(const void* g, void* l) {
    __builtin_amdgcn_global_load_lds(
        (__attribute__((address_space(1))) void*)(g),
        (__attribute__((address_space(3))) void*)(l), 16, 0, 0);
}

// wave-level dtype sniff (uniform per wave): bf16 weights -> sane exponents.
__device__ __forceinline__ int sniff(const void* wnode) {
    const u16* w = (const u16*)wnode;
    int lane = threadIdx.x & 63;
    u16 u = w[2 * lane];
    int e = (u >> 7) & 0xFF;
    unsigned long long m = __ballot(e >= 100 && e <= 140);
    return __popcll(m) >= 48;
}

// -------- k_gat: h = x@W[l]; s1 = h@a1; s2 = h@a2 ---------------------------
// 1024 blocks x 256 thr. Block = 4 rows x 256 cols. Wave w = row w exactly;
// thread covers cols 4tx..4tx+3. x broadcast wave-uniform from xs[w][k].
// Barrier-free k-loop, direct global W. 4 blocks/CU -> 4 waves/SIMD TLP.
__global__ __launch_bounds__(256) void k_gat(
    const float* __restrict__ x, const void* __restrict__ gat_W,
    const void* __restrict__ gat_a, int layer,
    const void* __restrict__ nf, const void* __restrict__ Wn_raw,
    const void* __restrict__ bn, int first,
    float* __restrict__ h, float* __restrict__ s1, float* __restrict__ s2) {
    __shared__ float xs[4][256];
    const int t = threadIdx.x, bx = blockIdx.x;
    const int row0 = bx * 4;
    const int w = t >> 6, tx = t & 63, c0 = 4 * tx;
    const int isbf = sniff(Wn_raw);
    float acc[4];

    if (isbf) {
        if (first) {
            // xs <- nf rows (k<78); then x0 = nf@Wn + b computed into regs
            const u16* nfu = (const u16*)nf;
            for (int i = t; i < 312; i += 256) {
                int r = i / 78, k = i - r * 78;
                xs[r][k] = bu2f(nfu[(row0 + r) * 78 + k]);
            }
            __syncthreads();
            const u16* Wnl = (const u16*)Wn_raw;
            const __hip_bfloat16* bnb = (const __hip_bfloat16*)bn;
            #pragma unroll
            for (int j = 0; j < 4; ++j) acc[j] = b2f(bnb[c0 + j]);
            #pragma unroll 2
            for (int k = 0; k < 78; ++k) {
                uint2 wv = *(const uint2*)(Wnl + k * 256 + c0);
                float w0 = __uint_as_float(wv.x << 16);
                float w1 = __uint_as_float(wv.x & 0xffff0000u);
                float w2 = __uint_as_float(wv.y << 16);
                float w3 = __uint_as_float(wv.y & 0xffff0000u);
                float xv = xs[w][k];
                acc[0] += xv * w0; acc[1] += xv * w1;
                acc[2] += xv * w2; acc[3] += xv * w3;
            }
            __syncthreads();              // done reading nf from xs
            *(float4*)&xs[w][c0] = (float4){acc[0], acc[1], acc[2], acc[3]};
            __syncthreads();
        } else {
            int r = t >> 6, pos = t & 63;  // wave w stages row w: coalesced 1 KB
            ((float4*)&xs[r][0])[pos] = ((const float4*)&x[(size_t)(row0 + r) * 256])[pos];
            __syncthreads();
        }
        // barrier-free k-loop
        const u16* Wl = (const u16*)gat_W + (size_t)layer * 65536;
        #pragma unroll
        for (int j = 0; j < 4; ++j) acc[j] = 0.f;
        #pragma unroll 4
        for (int k = 0; k < 256; ++k) {
            uint2 wv = *(const uint2*)(Wl + k * 256 + c0);
            float w0 = __uint_as_float(wv.x << 16);
            float w1 = __uint_as_float(wv.x & 0xffff0000u);
            float w2 = __uint_as_float(wv.y << 16);
            float w3 = __uint_as_float(wv.y & 0xffff0000u);
            float xv = xs[w][k];
            acc[0] += xv * w0; acc[1] += xv * w1;
            acc[2] += xv * w2; acc[3] += xv * w3;
        }
        // epilogue: s1/s2 full-wave reduce (wave = 1 row, lanes cover all cols)
        const __hip_bfloat16* ga = (const __hip_bfloat16*)gat_a + (size_t)layer * 512;
        float d1 = 0.f, d2 = 0.f;
        #pragma unroll
        for (int j = 0; j < 4; ++j) {
            d1 += acc[j] * b2f(ga[c0 + j]);
            d2 += acc[j] * b2f(ga[256 + c0 + j]);
        }
        #pragma unroll
        for (int off = 1; off < 64; off <<= 1) {
            d1 += __shfl_xor(d1, off, 64);
            d2 += __shfl_xor(d2, off, 64);
        }
        if (tx == 0) { s1[row0 + w] = d1; s2[row0 + w] = d2; }
        *(float4*)&h[(size_t)(row0 + w) * 256 + c0] = (float4){acc[0], acc[1], acc[2], acc[3]};
    } else {
        // ---------------- f32 fallback (correct, unoptimized) ----------------
        const float* Wlf = (const float*)gat_W + (size_t)layer * 65536;
        const float* gaf = (const float*)gat_a + (size_t)layer * 512;
        if (first) {
            const float* nff = (const float*)nf;
            for (int i = t; i < 312; i += 256) {
                int r = i / 78, k = i - r * 78;
                xs[r][k] = nff[(row0 + r) * 78 + k];
            }
            __syncthreads();
            const float* Wnf = (const float*)Wn_raw;
            const float* bnf = (const float*)bn;
            #pragma unroll
            for (int j = 0; j < 4; ++j) acc[j] = bnf[c0 + j];
            for (int k = 0; k < 78; ++k) {
                float4 wf = *(const float4*)(Wnf + k * 256 + c0);
                float xv = xs[w][k];
                acc[0] += xv * wf.x; acc[1] += xv * wf.y;
                acc[2] += xv * wf.z; acc[3] += xv * wf.w;
            }
            __syncthreads();
            *(float4*)&xs[w][c0] = (float4){acc[0], acc[1], acc[2], acc[3]};
            __syncthreads();
        } else {
            int r = t >> 6, pos = t & 63;
            ((float4*)&xs[r][0])[pos] = ((const float4*)&x[(size_t)(row0 + r) * 256])[pos];
            __syncthreads();
        }
        #pragma unroll
        for (int j = 0; j < 4; ++j) acc[j] = 0.f;
        #pragma unroll 4
        for (int k = 0; k < 256; ++k) {
            float4 wf = *(const float4*)(Wlf + k * 256 + c0);
            float xv = xs[w][k];
            acc[0] += xv * wf.x; acc[1] += xv * wf.y;
            acc[2] += xv * wf.z; acc[3] += xv * wf.w;
        }
        float d1 = 0.f, d2 = 0.f;
        #pragma unroll
        for (int j = 0; j < 4; ++j) {
            d1 += acc[j] * gaf[c0 + j];
            d2 += acc[j] * gaf[256 + c0 + j];
        }
        #pragma unroll
        for (int off = 1; off < 64; off <<= 1) {
            d1 += __shfl_xor(d1, off, 64);
            d2 += __shfl_xor(d2, off, 64);
        }
        if (tx == 0) { s1[row0 + w] = d1; s2[row0 + w] = d2; }
        *(float4*)&h[(size_t)(row0 + w) * 256 + c0] = (float4){acc[0], acc[1], acc[2], acc[3]};
    }
}

// ---------------- attn: softmax(mask(leaky(s1+s2))) @ h ---------------------
__global__ __launch_bounds__(256) void k_attn(
    const float* __restrict__ h, const float* __restrict__ s1,
    const float* __restrict__ s2, const int* __restrict__ adj,
    float* __restrict__ x, float* __restrict__ gpart, int do_pool) {
    __shared__ float att_t[128][10];
    __shared__ __align__(16) float hbuf[2][32 * 256];
    __shared__ float pool_red[4][256];
    int blk = blockIdx.x, b = blk >> 4, i0 = (blk & 15) << 3;
    int t = threadIdx.x, w = t >> 6, lane = t & 63;
    const char* hbytes = (const char*)(h + (size_t)b * 32768);
    const int ph = blk & 3;
    {
        char* lb = (char*)&hbuf[0][0];
        const char* g = hbytes + ph * 32768;
        #pragma unroll
        for (int i = 0; i < 8; ++i)
            async16(g + i * 4096 + t * 16, lb + i * 4096 + t * 16);
    }
    {
        int cc0 = lane, cc1 = lane + 64;
        int ir0 = i0 + 2 * w, ir1 = ir0 + 1;
        const int* a0 = adj + (size_t)(b * 128 + ir0) * 128;
        const int* a1 = adj + (size_t)(b * 128 + ir1) * 128;
        int m00 = a0[cc0], m01 = a0[cc1], m10 = a1[cc0], m11 = a1[cc1];
        float sv0 = s1[b * 128 + ir0], sv1 = s1[b * 128 + ir1];
        float t0 = s2[b * 128 + cc0],  t1 = s2[b * 128 + cc1];
        float e00 = sv0 + t0; e00 = (e00 >= 0.f) ? e00 : 0.2f * e00;
        float e01 = sv0 + t1; e01 = (e01 >= 0.f) ? e01 : 0.2f * e01;
        float e10 = sv1 + t0; e10 = (e10 >= 0.f) ? e10 : 0.2f * e10;
        float e11 = sv1 + t1; e11 = (e11 >= 0.f) ? e11 : 0.2f * e11;
        float v00 = (m00 > 0) ? e00 : NEG_INF;
        float v01 = (m01 > 0) ? e01 : NEG_INF;
        float v10 = (m10 > 0) ? e10 : NEG_INF;
        float v11 = (m11 > 0) ? e11 : NEG_INF;
        float mx0 = fmaxf(v00, v01), mx1 = fmaxf(v10, v11);
        #pragma unroll
        for (int off = 1; off < 64; off <<= 1) {
            mx0 = fmaxf(mx0, __shfl_xor(mx0, off, 64));
            mx1 = fmaxf(mx1, __shfl_xor(mx1, off, 64));
        }
        float p00 = __expf(v00 - mx0), p01 = __expf(v01 - mx0);
        float p10 = __expf(v10 - mx1), p11 = __expf(v11 - mx1);
        float s0 = p00 + p01, ss1 = p10 + p11;
        #pragma unroll
        for (int off = 1; off < 64; off <<= 1) {
            s0  += __shfl_xor(s0, off, 64);
            ss1 += __shfl_xor(ss1, off, 64);
        }
        float inv0 = 1.0f / s0, inv1 = 1.0f / ss1;
        att_t[cc0][2 * w]     = p00 * inv0;
        att_t[cc1][2 * w]     = p01 * inv0;
        att_t[cc0][2 * w + 1] = p10 * inv1;
        att_t[cc1][2 * w + 1] = p11 * inv1;
    }
    __syncthreads();
    int tx = t & 63, ty = t >> 6;
    float acc0[4] = {0.f, 0.f, 0.f, 0.f}, acc1[4] = {0.f, 0.f, 0.f, 0.f};
    for (int c = 0; c < 4; ++c) {
        if (c < 3) {
            char* lb = (char*)&hbuf[(c + 1) & 1][0];
            const char* g = hbytes + (((c + 1 + ph) & 3) * 32768);
            #pragma unroll
            for (int i = 0; i < 8; ++i)
                async16(g + i * 4096 + t * 16, lb + i * 4096 + t * 16);
        }
        const float* hc = &hbuf[c & 1][0];
        const int jb = ((c + ph) & 3) * 32;
        #pragma unroll 4
        for (int jj = 0; jj < 32; ++jj) {
            float4 hv = *(const float4*)&hc[jj * 256 + 4 * tx];
            float2 ap = *(const float2*)&att_t[jb + jj][2 * ty];
            acc0[0] += ap.x * hv.x; acc0[1] += ap.x * hv.y;
            acc0[2] += ap.x * hv.z; acc0[3] += ap.x * hv.w;
            acc1[0] += ap.y * hv.x; acc1[1] += ap.y * hv.y;
            acc1[2] += ap.y * hv.z; acc1[3] += ap.y * hv.w;
        }
        __syncthreads();
    }
    if (!do_pool) {
        float4 o0 = {fmaxf(acc0[0],0.f), fmaxf(acc0[1],0.f), fmaxf(acc0[2],0.f), fmaxf(acc0[3],0.f)};
        float4 o1 = {fmaxf(acc1[0],0.f), fmaxf(acc1[1],0.f), fmaxf(acc1[2],0.f), fmaxf(acc1[3],0.f)};
        *(float4*)&x[(size_t)(b * 128 + i0 + 2 * ty)     * 256 + 4 * tx] = o0;
        *(float4*)&x[(size_t)(b * 128 + i0 + 2 * ty + 1) * 256 + 4 * tx] = o1;
    } else {
        float4 pr = {(fmaxf(acc0[0],0.f) + fmaxf(acc1[0],0.f)) * (1.f/128.f),
                     (fmaxf(acc0[1],0.f) + fmaxf(acc1[1],0.f)) * (1.f/128.f),
                     (fmaxf(acc0[2],0.f) + fmaxf(acc1[2],0.f)) * (1.f/128.f),
                     (fmaxf(acc0[3],0.f) + fmaxf(acc1[3],0.f)) * (1.f/128.f)};
        *(float4*)&pool_red[ty][4 * tx] = pr;
        __syncthreads();
        if (t < 64) {
            float4 r0 = ((const float4*)&pool_red[0][0])[t];
            float4 r1 = ((const float4*)&pool_red[1][0])[t];
            float4 r2 = ((const float4*)&pool_red[2][0])[t];
            float4 r3 = ((const float4*)&pool_red[3][0])[t];
            float4 o = {r0.x+r1.x+r2.x+r3.x, r0.y+r1.y+r2.y+r3.y,
                        r0.z+r1.z+r2.z+r3.z, r0.w+r1.w+r2.w+r3.w};
            *(float4*)&gpart[((size_t)b * 16 + (blk & 15)) * 256 + 4 * t] = o;
        }
    }
}

// ---------------- head: pool MLPs + concat + out MLP ------------------------
template <typename T>
__device__ __forceinline__ void head_body(
    int b, int t, const float* __restrict__ gpart,
    const T* scaf, const T* W_sc, const T* b_sc,
    const T* gp_w1, const T* gp_b1, const T* gp_w2, const T* gp_b2,
    const T* out_w1, const T* out_b1, const T* out_w2, const T* out_b2,
    float* gin_s, float* sproj, float* scaf_s,
    float* red1, float* red2, float* z1g, float* z1s,
    float* cvec, float* hdn, float* outv) {
    float g = 0.f;
    #pragma unroll
    for (int gg = 0; gg < 16; ++gg) g += gpart[((size_t)b * 16 + gg) * 256 + t];
    gin_s[t] = g;
    if (t < 20) scaf_s[t] = ldv(scaf, b * 20 + t);
    __syncthreads();
    {
        float sa = ldv(b_sc, t);
        #pragma unroll
        for (int k = 0; k < 20; ++k) sa += scaf_s[k] * ldv(W_sc, k * 256 + t);
        sproj[t] = sa;
    }
    __syncthreads();
    {
        int j = t & 127, khalf = t >> 7;
        int k0 = khalf * 128;
        float a1 = 0.f, a2 = 0.f;
        #pragma unroll 16
        for (int kk = 0; kk < 128; ++kk) {
            int k = k0 + kk;
            float wv = ldv(gp_w1, k * 128 + j);
            a1 += gin_s[k] * wv;
            a2 += sproj[k] * wv;
        }
        red1[t] = a1; red2[t] = a2;
    }
    __syncthreads();
    if (t < 128) {
        float bb = ldv(gp_b1, t);
        z1g[t] = fmaxf(bb + red1[t] + red1[t + 128], 0.f);
        z1s[t] = fmaxf(bb + red2[t] + red2[t + 128], 0.f);
    }
    __syncthreads();
    {
        int j = t & 63, q = t >> 6;
        int k0 = q * 32;
        float a1 = 0.f, a2 = 0.f;
        #pragma unroll
        for (int kk = 0; kk < 32; ++kk) {
            int k = k0 + kk;
            float wv = ldv(gp_w2, k * 64 + j);
            a1 += z1g[k] * wv;
            a2 += z1s[k] * wv;
        }
        red1[t] = a1; red2[t] = a2;
    }
    __syncthreads();
    if (t < 64) {
        float bb = ldv(gp_b2, t);
        cvec[t]      = fmaxf(bb + red1[t] + red1[t + 64] + red1[t + 128] + red1[t + 192], 0.f);
        cvec[64 + t] = fmaxf(bb + red2[t] + red2[t + 64] + red2[t + 128] + red2[t + 192], 0.f);
    }
    __syncthreads();
    {
        int j = t & 127, khalf = t >> 7;
        int k0 = khalf * 64;
        float a = 0.f;
        #pragma unroll 16
        for (int kk = 0; kk < 64; ++kk) {
            int k = k0 + kk;
            a += cvec[k] * ldv(out_w1, k * 128 + j);
        }
        red1[t] = a;
    }
    __syncthreads();
    if (t < 128) hdn[t] = fmaxf(ldv(out_b1, t) + red1[t] + red1[t + 128], 0.f);
    __syncthreads();
    if (t < 13) {
        float a = ldv(out_b2, t);
        #pragma unroll 16
        for (int k = 0; k < 128; ++k) a += hdn[k] * ldv(out_w2, k * 13 + t);
        outv[t] = a;
    }
}

__global__ __launch_bounds__(256) void k_head(
    const float* __restrict__ gpart, const void* __restrict__ scaf,
    const void* __restrict__ W_sc, const void* __restrict__ b_sc,
    const void* __restrict__ gp_w1, const void* __restrict__ gp_b1,
    const void* __restrict__ gp_w2, const void* __restrict__ gp_b2,
    const void* __restrict__ out_w1, const void* __restrict__ out_b1,
    const void* __restrict__ out_w2, const void* __restrict__ out_b2,
    void* __restrict__ out, const void* __restrict__ Wn) {
    int isbf = sniff(Wn);
    int b = blockIdx.x;
    int t = threadIdx.x;
    __shared__ float gin_s[256], sproj[256], scaf_s[20];
    __shared__ float red1[256], red2[256];
    __shared__ float z1g[128], z1s[128], cvec[128], hdn[128], outv[13];
    if (isbf) {
        head_body<__hip_bfloat16>(b, t, gpart,
            (const __hip_bfloat16*)scaf, (const __hip_bfloat16*)W_sc, (const __hip_bfloat16*)b_sc,
            (const __hip_bfloat16*)gp_w1, (const __hip_bfloat16*)gp_b1,
            (const __hip_bfloat16*)gp_w2, (const __hip_bfloat16*)gp_b2,
            (const __hip_bfloat16*)out_w1, (const __hip_bfloat16*)out_b1,
            (const __hip_bfloat16*)out_w2, (const __hip_bfloat16*)out_b2,
            gin_s, sproj, scaf_s, red1, red2, z1g, z1s, cvec, hdn, outv);
    } else {
        head_body<float>(b, t, gpart,
            (const float*)scaf, (const float*)W_sc, (const float*)b_sc,
            (const float*)gp_w1, (const float*)gp_b1,
            (const float*)gp_w2, (const float*)gp_b2,
            (const float*)out_w1, (const float*)out_b1,
            (const float*)out_w2, (const float*)out_b2,
            gin_s, sproj, scaf_s, red1, red2, z1g, z1s, cvec, hdn, outv);
    }
    __syncthreads();
    if (t < 13) {
        if (isbf) ((__hip_bfloat16*)out)[b * 13 + t] = __float2bfloat16(outv[t]);
        else      ((float*)out)[b * 13 + t] = outv[t];
    }
}

extern "C" void kernel_launch(void* const* d_in, const int* in_sizes, int n_in,
                              void* d_out, int out_size, void* d_ws, size_t ws_size,
                              hipStream_t stream) {
    (void)in_sizes; (void)n_in; (void)out_size; (void)ws_size;
    const void* nf     = d_in[0];
    const int*  adj    = (const int*)d_in[2];
    const void* scaf   = d_in[3];
    const void* W_node = d_in[4];
    const void* b_node = d_in[5];
    const void* gat_W  = d_in[6];
    const void* gat_a  = d_in[7];
    const void* W_sc   = d_in[8];
    const void* b_sc   = d_in[9];
    const void* gp_w1  = d_in[10];
    const void* gp_b1  = d_in[11];
    const void* gp_w2  = d_in[12];
    const void* gp_b2  = d_in[13];
    const void* out_w1 = d_in[14];
    const void* out_b1 = d_in[15];
    const void* out_w2 = d_in[16];
    const void* out_b2 = d_in[17];

    float* ws    = (float*)d_ws;
    float* x     = ws;                      // 1048576 f32
    float* h     = ws + 1048576;            // 1048576 f32
    float* s1    = ws + 2097152;            // 4096
    float* s2    = s1 + 4096;               // 4096
    float* gpart = s2 + 4096;               // 131072

    for (int l = 0; l < 3; ++l) {
        k_gat<<<1024, 256, 0, stream>>>(x, gat_W, gat_a, l,
                                        nf, W_node, b_node, (l == 0) ? 1 : 0,
                                        h, s1, s2);
        k_attn<<<512, 256, 0, stream>>>(h, s1, s2, adj, x, gpart, (l == 2) ? 1 : 0);
    }
    k_head<<<32, 256, 0, stream>>>(gpart, scaf, W_sc, b_sc, gp_w1, gp_b1, gp_w2, gp_b2,
                                   out_w1, out_b1, out_w2, out_b2, d_out, W_node);
}

// Round 11
// 228.997 us; speedup vs baseline: 1.1215x; 1.1215x over previous
//
#include <hip/hip_runtime.h>
#include <hip/hip_bf16.h>

#define NEG_INF -9.0e15f

using u16 = unsigned short;

__device__ __forceinline__ float b2f(__hip_bfloat16 v) { return __bfloat162float(v); }
__device__ __forceinline__ float ldv(const float* p, int i) { return p[i]; }
__device__ __forceinline__ float ldv(const __hip_bfloat16* p, int i) { return __bfloat162float(p[i]); }
__device__ __forceinline__ float bu2f(u16 u) { return __uint_as_float(((unsigned)u) << 16); }

__device__ __forceinline__ void unpack8u(uint4 r, float* f) {
    f[0]=__uint_as_float(r.x<<16); f[1]=__uint_as_float(r.x&0xffff0000u);
    f[2]=__uint_as_float(r.y<<16); f[3]=__uint_as_float(r.y&0xffff0000u);
    f[4]=__uint_as_float(r.z<<16); f[5]=__uint_as_float(r.z&0xffff0000u);
    f[6]=__uint_as_float(r.w<<16); f[7]=__uint_as_float(r.w&0xffff0000u);
}

__device__ __forceinline__ void async16(const void* g, void* l) {
    __builtin_amdgcn_global_load_lds(
        (__attribute__((address_space(1))) void*)(g),
        (__attribute__((address_space(3))) void*)(l), 16, 0, 0);
}

// wave-level dtype sniff (uniform per wave): bf16 weights -> sane exponents.
__device__ __forceinline__ int sniff(const void* wnode) {
    const u16* w = (const u16*)wnode;
    int lane = threadIdx.x & 63;
    u16 u = w[2 * lane];
    int e = (u >> 7) & 0xFF;
    unsigned long long m = __ballot(e >= 100 && e <= 140);
    return __popcll(m) >= 48;
}

// -------- k_gat: h = x@W[l]; s1 = h@a1; s2 = h@a2 ---------------------------
// 512 blocks x 128 thr. Block = 8 rows x 256 cols. Thread = 2 rows x 8 cols
// (rg = t>>5 -> rows 2rg,2rg+1; cg = t&31 -> cols 8cg..8cg+7).
// W staged in 8 x 16KB k-chunks via async16 dbuf; x transposed in LDS so the
// inner loop is 1 b64 + 1 b128 LDS per 16 FMA. Barrier only per chunk.
__global__ __launch_bounds__(128) void k_gat(
    const float* __restrict__ x, const void* __restrict__ gat_W,
    const void* __restrict__ gat_a, int layer,
    const void* __restrict__ nf, const void* __restrict__ Wn_raw,
    const void* __restrict__ bn, int first,
    float* __restrict__ h, float* __restrict__ s1, float* __restrict__ s2) {
    __shared__ __align__(16) char smem[8192 + 32768 + 2560];
    float* xsT = (float*)smem;                    // [256][8]   (bf16 path)
    char*  wb  = smem + 8192;                     // 2 x 16 KB W chunks
    float* nfs = (float*)(smem + 8192 + 32768);   // [8][80]

    const int t = threadIdx.x, bx = blockIdx.x;
    const int row0 = bx * 8;
    const int rg = t >> 5, cg = t & 31, c0 = 8 * cg;
    const int isbf = sniff(Wn_raw);
    float acc0[8], acc1[8];

    if (isbf) {
        const u16* Wl = (const u16*)gat_W + (size_t)layer * 65536;
        // issue stage of W chunk 0 (overlaps xsT preparation)
        {
            const char* g = (const char*)Wl;
            #pragma unroll
            for (int i = 0; i < 8; ++i)
                async16(g + i * 2048 + t * 16, wb + i * 2048 + t * 16);
        }
        if (first) {
            const u16* nfu = (const u16*)nf;
            for (int i = t; i < 624; i += 128) {
                int r = i / 78, k = i - r * 78;
                nfs[r * 80 + k] = bu2f(nfu[(row0 + r) * 78 + k]);
            }
            __syncthreads();
            const u16* Wnl = (const u16*)Wn_raw;
            float b8[8];
            unpack8u(*(const uint4*)((const u16*)bn + c0), b8);
            #pragma unroll
            for (int j = 0; j < 8; ++j) { acc0[j] = b8[j]; acc1[j] = b8[j]; }
            #pragma unroll 2
            for (int k = 0; k < 78; ++k) {
                float w8[8];
                unpack8u(*(const uint4*)(Wnl + k * 256 + c0), w8);
                float x0 = nfs[(2 * rg) * 80 + k], x1 = nfs[(2 * rg + 1) * 80 + k];
                #pragma unroll
                for (int j = 0; j < 8; ++j) {
                    acc0[j] += x0 * w8[j];
                    acc1[j] += x1 * w8[j];
                }
            }
            #pragma unroll
            for (int j = 0; j < 8; ++j) {
                xsT[(c0 + j) * 8 + 2 * rg]     = acc0[j];
                xsT[(c0 + j) * 8 + 2 * rg + 1] = acc1[j];
            }
            __syncthreads();   // xsT ready + W chunk 0 staged
        } else {
            int row = t >> 4, kb = (t & 15) * 16;
            const float4* xp = (const float4*)(x + (size_t)(row0 + row) * 256 + kb);
            #pragma unroll
            for (int q = 0; q < 4; ++q) {
                float4 f = xp[q];
                xsT[(kb + 4 * q + 0) * 8 + row] = f.x;
                xsT[(kb + 4 * q + 1) * 8 + row] = f.y;
                xsT[(kb + 4 * q + 2) * 8 + row] = f.z;
                xsT[(kb + 4 * q + 3) * 8 + row] = f.w;
            }
            __syncthreads();
        }
        #pragma unroll
        for (int j = 0; j < 8; ++j) { acc0[j] = 0.f; acc1[j] = 0.f; }
        for (int c = 0; c < 8; ++c) {
            if (c < 7) {
                const char* g = (const char*)Wl + (c + 1) * 16384;
                char* lb = wb + ((c + 1) & 1) * 16384;
                #pragma unroll
                for (int i = 0; i < 8; ++i)
                    async16(g + i * 2048 + t * 16, lb + i * 2048 + t * 16);
            }
            const u16* wc = (const u16*)(wb + (c & 1) * 16384);
            const float* xk = xsT + (c * 32) * 8 + 2 * rg;
            #pragma unroll 4
            for (int kk = 0; kk < 32; ++kk) {
                float w8[8];
                unpack8u(*(const uint4*)(wc + kk * 256 + c0), w8);
                float2 xv = *(const float2*)(xk + kk * 8);
                #pragma unroll
                for (int j = 0; j < 8; ++j) {
                    acc0[j] += xv.x * w8[j];
                    acc1[j] += xv.y * w8[j];
                }
            }
            __syncthreads();   // drains stage(c+1), releases wb[c&1]
        }
        // epilogue: s1/s2 + h store
        const u16* ga = (const u16*)gat_a + (size_t)layer * 512;
        float a1v[8], a2v[8];
        unpack8u(*(const uint4*)(ga + c0), a1v);
        unpack8u(*(const uint4*)(ga + 256 + c0), a2v);
        float d10 = 0.f, d20 = 0.f, d11 = 0.f, d21 = 0.f;
        #pragma unroll
        for (int j = 0; j < 8; ++j) {
            d10 += acc0[j] * a1v[j]; d20 += acc0[j] * a2v[j];
            d11 += acc1[j] * a1v[j]; d21 += acc1[j] * a2v[j];
        }
        #pragma unroll
        for (int off = 1; off < 32; off <<= 1) {   // reduce within 32-lane half
            d10 += __shfl_xor(d10, off, 64); d20 += __shfl_xor(d20, off, 64);
            d11 += __shfl_xor(d11, off, 64); d21 += __shfl_xor(d21, off, 64);
        }
        if (cg == 0) {
            s1[row0 + 2 * rg] = d10;     s2[row0 + 2 * rg] = d20;
            s1[row0 + 2 * rg + 1] = d11; s2[row0 + 2 * rg + 1] = d21;
        }
        *(float4*)&h[(size_t)(row0 + 2 * rg) * 256 + c0]         = (float4){acc0[0], acc0[1], acc0[2], acc0[3]};
        *(float4*)&h[(size_t)(row0 + 2 * rg) * 256 + c0 + 4]     = (float4){acc0[4], acc0[5], acc0[6], acc0[7]};
        *(float4*)&h[(size_t)(row0 + 2 * rg + 1) * 256 + c0]     = (float4){acc1[0], acc1[1], acc1[2], acc1[3]};
        *(float4*)&h[(size_t)(row0 + 2 * rg + 1) * 256 + c0 + 4] = (float4){acc1[4], acc1[5], acc1[6], acc1[7]};
    } else {
        // ---------------- f32 fallback (correct, unoptimized) ----------------
        float* xs = (float*)smem;   // [8][256]
        const float* Wlf = (const float*)gat_W + (size_t)layer * 65536;
        const float* gaf = (const float*)gat_a + (size_t)layer * 512;
        if (first) {
            const float* nff = (const float*)nf;
            for (int i = t; i < 624; i += 128) {
                int r = i / 78, k = i - r * 78;
                nfs[r * 80 + k] = nff[(row0 + r) * 78 + k];
            }
            __syncthreads();
            const float* Wnf = (const float*)Wn_raw;
            const float* bnf = (const float*)bn;
            #pragma unroll
            for (int j = 0; j < 8; ++j) { acc0[j] = bnf[c0 + j]; acc1[j] = acc0[j]; }
            for (int k = 0; k < 78; ++k) {
                float4 w0 = *(const float4*)(Wnf + k * 256 + c0);
                float4 w1 = *(const float4*)(Wnf + k * 256 + c0 + 4);
                float wf[8] = {w0.x, w0.y, w0.z, w0.w, w1.x, w1.y, w1.z, w1.w};
                float x0 = nfs[(2 * rg) * 80 + k], x1 = nfs[(2 * rg + 1) * 80 + k];
                #pragma unroll
                for (int j = 0; j < 8; ++j) { acc0[j] += x0 * wf[j]; acc1[j] += x1 * wf[j]; }
            }
            __syncthreads();
            #pragma unroll
            for (int j = 0; j < 8; ++j) {
                xs[(2 * rg) * 256 + c0 + j]     = acc0[j];
                xs[(2 * rg + 1) * 256 + c0 + j] = acc1[j];
            }
            __syncthreads();
        } else {
            int row = t >> 4, kb = (t & 15) * 16;
            #pragma unroll
            for (int q = 0; q < 4; ++q)
                ((float4*)(xs + row * 256 + kb))[q] =
                    ((const float4*)(x + (size_t)(row0 + row) * 256 + kb))[q];
            __syncthreads();
        }
        #pragma unroll
        for (int j = 0; j < 8; ++j) { acc0[j] = 0.f; acc1[j] = 0.f; }
        #pragma unroll 4
        for (int k = 0; k < 256; ++k) {
            float4 w0 = *(const float4*)(Wlf + k * 256 + c0);
            float4 w1 = *(const float4*)(Wlf + k * 256 + c0 + 4);
            float wf[8] = {w0.x, w0.y, w0.z, w0.w, w1.x, w1.y, w1.z, w1.w};
            float x0 = xs[(2 * rg) * 256 + k], x1 = xs[(2 * rg + 1) * 256 + k];
            #pragma unroll
            for (int j = 0; j < 8; ++j) { acc0[j] += x0 * wf[j]; acc1[j] += x1 * wf[j]; }
        }
        float d10 = 0.f, d20 = 0.f, d11 = 0.f, d21 = 0.f;
        #pragma unroll
        for (int j = 0; j < 8; ++j) {
            float a1v = gaf[c0 + j], a2v = gaf[256 + c0 + j];
            d10 += acc0[j] * a1v; d20 += acc0[j] * a2v;
            d11 += acc1[j] * a1v; d21 += acc1[j] * a2v;
        }
        #pragma unroll
        for (int off = 1; off < 32; off <<= 1) {
            d10 += __shfl_xor(d10, off, 64); d20 += __shfl_xor(d20, off, 64);
            d11 += __shfl_xor(d11, off, 64); d21 += __shfl_xor(d21, off, 64);
        }
        if (cg == 0) {
            s1[row0 + 2 * rg] = d10;     s2[row0 + 2 * rg] = d20;
            s1[row0 + 2 * rg + 1] = d11; s2[row0 + 2 * rg + 1] = d21;
        }
        *(float4*)&h[(size_t)(row0 + 2 * rg) * 256 + c0]         = (float4){acc0[0], acc0[1], acc0[2], acc0[3]};
        *(float4*)&h[(size_t)(row0 + 2 * rg) * 256 + c0 + 4]     = (float4){acc0[4], acc0[5], acc0[6], acc0[7]};
        *(float4*)&h[(size_t)(row0 + 2 * rg + 1) * 256 + c0]     = (float4){acc1[0], acc1[1], acc1[2], acc1[3]};
        *(float4*)&h[(size_t)(row0 + 2 * rg + 1) * 256 + c0 + 4] = (float4){acc1[4], acc1[5], acc1[6], acc1[7]};
    }
}

// ---------------- attn: softmax(mask(leaky(s1+s2))) @ h ---------------------
__global__ __launch_bounds__(256) void k_attn(
    const float* __restrict__ h, const float* __restrict__ s1,
    const float* __restrict__ s2, const int* __restrict__ adj,
    float* __restrict__ x, float* __restrict__ gpart, int do_pool) {
    __shared__ float att_t[128][10];
    __shared__ __align__(16) float hbuf[2][32 * 256];
    __shared__ float pool_red[4][256];
    int blk = blockIdx.x, b = blk >> 4, i0 = (blk & 15) << 3;
    int t = threadIdx.x, w = t >> 6, lane = t & 63;
    const char* hbytes = (const char*)(h + (size_t)b * 32768);
    const int ph = blk & 3;
    {
        char* lb = (char*)&hbuf[0][0];
        const char* g = hbytes + ph * 32768;
        #pragma unroll
        for (int i = 0; i < 8; ++i)
            async16(g + i * 4096 + t * 16, lb + i * 4096 + t * 16);
    }
    {
        int cc0 = lane, cc1 = lane + 64;
        int ir0 = i0 + 2 * w, ir1 = ir0 + 1;
        const int* a0 = adj + (size_t)(b * 128 + ir0) * 128;
        const int* a1 = adj + (size_t)(b * 128 + ir1) * 128;
        int m00 = a0[cc0], m01 = a0[cc1], m10 = a1[cc0], m11 = a1[cc1];
        float sv0 = s1[b * 128 + ir0], sv1 = s1[b * 128 + ir1];
        float t0 = s2[b * 128 + cc0],  t1 = s2[b * 128 + cc1];
        float e00 = sv0 + t0; e00 = (e00 >= 0.f) ? e00 : 0.2f * e00;
        float e01 = sv0 + t1; e01 = (e01 >= 0.f) ? e01 : 0.2f * e01;
        float e10 = sv1 + t0; e10 = (e10 >= 0.f) ? e10 : 0.2f * e10;
        float e11 = sv1 + t1; e11 = (e11 >= 0.f) ? e11 : 0.2f * e11;
        float v00 = (m00 > 0) ? e00 : NEG_INF;
        float v01 = (m01 > 0) ? e01 : NEG_INF;
        float v10 = (m10 > 0) ? e10 : NEG_INF;
        float v11 = (m11 > 0) ? e11 : NEG_INF;
        float mx0 = fmaxf(v00, v01), mx1 = fmaxf(v10, v11);
        #pragma unroll
        for (int off = 1; off < 64; off <<= 1) {
            mx0 = fmaxf(mx0, __shfl_xor(mx0, off, 64));
            mx1 = fmaxf(mx1, __shfl_xor(mx1, off, 64));
        }
        float p00 = __expf(v00 - mx0), p01 = __expf(v01 - mx0);
        float p10 = __expf(v10 - mx1), p11 = __expf(v11 - mx1);
        float s0 = p00 + p01, ss1 = p10 + p11;
        #pragma unroll
        for (int off = 1; off < 64; off <<= 1) {
            s0  += __shfl_xor(s0, off, 64);
            ss1 += __shfl_xor(ss1, off, 64);
        }
        float inv0 = 1.0f / s0, inv1 = 1.0f / ss1;
        att_t[cc0][2 * w]     = p00 * inv0;
        att_t[cc1][2 * w]     = p01 * inv0;
        att_t[cc0][2 * w + 1] = p10 * inv1;
        att_t[cc1][2 * w + 1] = p11 * inv1;
    }
    __syncthreads();
    int tx = t & 63, ty = t >> 6;
    float acc0[4] = {0.f, 0.f, 0.f, 0.f}, acc1[4] = {0.f, 0.f, 0.f, 0.f};
    for (int c = 0; c < 4; ++c) {
        if (c < 3) {
            char* lb = (char*)&hbuf[(c + 1) & 1][0];
            const char* g = hbytes + (((c + 1 + ph) & 3) * 32768);
            #pragma unroll
            for (int i = 0; i < 8; ++i)
                async16(g + i * 4096 + t * 16, lb + i * 4096 + t * 16);
        }
        const float* hc = &hbuf[c & 1][0];
        const int jb = ((c + ph) & 3) * 32;
        #pragma unroll 4
        for (int jj = 0; jj < 32; ++jj) {
            float4 hv = *(const float4*)&hc[jj * 256 + 4 * tx];
            float2 ap = *(const float2*)&att_t[jb + jj][2 * ty];
            acc0[0] += ap.x * hv.x; acc0[1] += ap.x * hv.y;
            acc0[2] += ap.x * hv.z; acc0[3] += ap.x * hv.w;
            acc1[0] += ap.y * hv.x; acc1[1] += ap.y * hv.y;
            acc1[2] += ap.y * hv.z; acc1[3] += ap.y * hv.w;
        }
        __syncthreads();
    }
    if (!do_pool) {
        float4 o0 = {fmaxf(acc0[0],0.f), fmaxf(acc0[1],0.f), fmaxf(acc0[2],0.f), fmaxf(acc0[3],0.f)};
        float4 o1 = {fmaxf(acc1[0],0.f), fmaxf(acc1[1],0.f), fmaxf(acc1[2],0.f), fmaxf(acc1[3],0.f)};
        *(float4*)&x[(size_t)(b * 128 + i0 + 2 * ty)     * 256 + 4 * tx] = o0;
        *(float4*)&x[(size_t)(b * 128 + i0 + 2 * ty + 1) * 256 + 4 * tx] = o1;
    } else {
        float4 pr = {(fmaxf(acc0[0],0.f) + fmaxf(acc1[0],0.f)) * (1.f/128.f),
                     (fmaxf(acc0[1],0.f) + fmaxf(acc1[1],0.f)) * (1.f/128.f),
                     (fmaxf(acc0[2],0.f) + fmaxf(acc1[2],0.f)) * (1.f/128.f),
                     (fmaxf(acc0[3],0.f) + fmaxf(acc1[3],0.f)) * (1.f/128.f)};
        *(float4*)&pool_red[ty][4 * tx] = pr;
        __syncthreads();
        if (t < 64) {
            float4 r0 = ((const float4*)&pool_red[0][0])[t];
            float4 r1 = ((const float4*)&pool_red[1][0])[t];
            float4 r2 = ((const float4*)&pool_red[2][0])[t];
            float4 r3 = ((const float4*)&pool_red[3][0])[t];
            float4 o = {r0.x+r1.x+r2.x+r3.x, r0.y+r1.y+r2.y+r3.y,
                        r0.z+r1.z+r2.z+r3.z, r0.w+r1.w+r2.w+r3.w};
            *(float4*)&gpart[((size_t)b * 16 + (blk & 15)) * 256 + 4 * t] = o;
        }
    }
}

// ---------------- head: pool MLPs + concat + out MLP ------------------------
template <typename T>
__device__ __forceinline__ void head_body(
    int b, int t, const float* __restrict__ gpart,
    const T* scaf, const T* W_sc, const T* b_sc,
    const T* gp_w1, const T* gp_b1, const T* gp_w2, const T* gp_b2,
    const T* out_w1, const T* out_b1, const T* out_w2, const T* out_b2,
    float* gin_s, float* sproj, float* scaf_s,
    float* red1, float* red2, float* z1g, float* z1s,
    float* cvec, float* hdn, float* outv) {
    float g = 0.f;
    #pragma unroll
    for (int gg = 0; gg < 16; ++gg) g += gpart[((size_t)b * 16 + gg) * 256 + t];
    gin_s[t] = g;
    if (t < 20) scaf_s[t] = ldv(scaf, b * 20 + t);
    __syncthreads();
    {
        float sa = ldv(b_sc, t);
        #pragma unroll
        for (int k = 0; k < 20; ++k) sa += scaf_s[k] * ldv(W_sc, k * 256 + t);
        sproj[t] = sa;
    }
    __syncthreads();
    {
        int j = t & 127, khalf = t >> 7;
        int k0 = khalf * 128;
        float a1 = 0.f, a2 = 0.f;
        #pragma unroll 16
        for (int kk = 0; kk < 128; ++kk) {
            int k = k0 + kk;
            float wv = ldv(gp_w1, k * 128 + j);
            a1 += gin_s[k] * wv;
            a2 += sproj[k] * wv;
        }
        red1[t] = a1; red2[t] = a2;
    }
    __syncthreads();
    if (t < 128) {
        float bb = ldv(gp_b1, t);
        z1g[t] = fmaxf(bb + red1[t] + red1[t + 128], 0.f);
        z1s[t] = fmaxf(bb + red2[t] + red2[t + 128], 0.f);
    }
    __syncthreads();
    {
        int j = t & 63, q = t >> 6;
        int k0 = q * 32;
        float a1 = 0.f, a2 = 0.f;
        #pragma unroll
        for (int kk = 0; kk < 32; ++kk) {
            int k = k0 + kk;
            float wv = ldv(gp_w2, k * 64 + j);
            a1 += z1g[k] * wv;
            a2 += z1s[k] * wv;
        }
        red1[t] = a1; red2[t] = a2;
    }
    __syncthreads();
    if (t < 64) {
        float bb = ldv(gp_b2, t);
        cvec[t]      = fmaxf(bb + red1[t] + red1[t + 64] + red1[t + 128] + red1[t + 192], 0.f);
        cvec[64 + t] = fmaxf(bb + red2[t] + red2[t + 64] + red2[t + 128] + red2[t + 192], 0.f);
    }
    __syncthreads();
    {
        int j = t & 127, khalf = t >> 7;
        int k0 = khalf * 64;
        float a = 0.f;
        #pragma unroll 16
        for (int kk = 0; kk < 64; ++kk) {
            int k = k0 + kk;
            a += cvec[k] * ldv(out_w1, k * 128 + j);
        }
        red1[t] = a;
    }
    __syncthreads();
    if (t < 128) hdn[t] = fmaxf(ldv(out_b1, t) + red1[t] + red1[t + 128], 0.f);
    __syncthreads();
    if (t < 13) {
        float a = ldv(out_b2, t);
        #pragma unroll 16
        for (int k = 0; k < 128; ++k) a += hdn[k] * ldv(out_w2, k * 13 + t);
        outv[t] = a;
    }
}

__global__ __launch_bounds__(256) void k_head(
    const float* __restrict__ gpart, const void* __restrict__ scaf,
    const void* __restrict__ W_sc, const void* __restrict__ b_sc,
    const void* __restrict__ gp_w1, const void* __restrict__ gp_b1,
    const void* __restrict__ gp_w2, const void* __restrict__ gp_b2,
    const void* __restrict__ out_w1, const void* __restrict__ out_b1,
    const void* __restrict__ out_w2, const void* __restrict__ out_b2,
    void* __restrict__ out, const void* __restrict__ Wn) {
    int isbf = sniff(Wn);
    int b = blockIdx.x;
    int t = threadIdx.x;
    __shared__ float gin_s[256], sproj[256], scaf_s[20];
    __shared__ float red1[256], red2[256];
    __shared__ float z1g[128], z1s[128], cvec[128], hdn[128], outv[13];
    if (isbf) {
        head_body<__hip_bfloat16>(b, t, gpart,
            (const __hip_bfloat16*)scaf, (const __hip_bfloat16*)W_sc, (const __hip_bfloat16*)b_sc,
            (const __hip_bfloat16*)gp_w1, (const __hip_bfloat16*)gp_b1,
            (const __hip_bfloat16*)gp_w2, (const __hip_bfloat16*)gp_b2,
            (const __hip_bfloat16*)out_w1, (const __hip_bfloat16*)out_b1,
            (const __hip_bfloat16*)out_w2, (const __hip_bfloat16*)out_b2,
            gin_s, sproj, scaf_s, red1, red2, z1g, z1s, cvec, hdn, outv);
    } else {
        head_body<float>(b, t, gpart,
            (const float*)scaf, (const float*)W_sc, (const float*)b_sc,
            (const float*)gp_w1, (const float*)gp_b1,
            (const float*)gp_w2, (const float*)gp_b2,
            (const float*)out_w1, (const float*)out_b1,
            (const float*)out_w2, (const float*)out_b2,
            gin_s, sproj, scaf_s, red1, red2, z1g, z1s, cvec, hdn, outv);
    }
    __syncthreads();
    if (t < 13) {
        if (isbf) ((__hip_bfloat16*)out)[b * 13 + t] = __float2bfloat16(outv[t]);
        else      ((float*)out)[b * 13 + t] = outv[t];
    }
}

extern "C" void kernel_launch(void* const* d_in, const int* in_sizes, int n_in,
                              void* d_out, int out_size, void* d_ws, size_t ws_size,
                              hipStream_t stream) {
    (void)in_sizes; (void)n_in; (void)out_size; (void)ws_size;
    const void* nf     = d_in[0];
    const int*  adj    = (const int*)d_in[2];
    const void* scaf   = d_in[3];
    const void* W_node = d_in[4];
    const void* b_node = d_in[5];
    const void* gat_W  = d_in[6];
    const void* gat_a  = d_in[7];
    const void* W_sc   = d_in[8];
    const void* b_sc   = d_in[9];
    const void* gp_w1  = d_in[10];
    const void* gp_b1  = d_in[11];
    const void* gp_w2  = d_in[12];
    const void* gp_b2  = d_in[13];
    const void* out_w1 = d_in[14];
    const void* out_b1 = d_in[15];
    const void* out_w2 = d_in[16];
    const void* out_b2 = d_in[17];

    float* ws    = (float*)d_ws;
    float* x     = ws;                      // 1048576 f32
    float* h     = ws + 1048576;            // 1048576 f32
    float* s1    = ws + 2097152;            // 4096
    float* s2    = s1 + 4096;               // 4096
    float* gpart = s2 + 4096;               // 131072

    for (int l = 0; l < 3; ++l) {
        k_gat<<<512, 128, 0, stream>>>(x, gat_W, gat_a, l,
                                       nf, W_node, b_node, (l == 0) ? 1 : 0,
                                       h, s1, s2);
        k_attn<<<512, 256, 0, stream>>>(h, s1, s2, adj, x, gpart, (l == 2) ? 1 : 0);
    }
    k_head<<<32, 256, 0, stream>>>(gpart, scaf, W_sc, b_sc, gp_w1, gp_b1, gp_w2, gp_b2,
                                   out_w1, out_b1, out_w2, out_b2, d_out, W_node);
}